// Round 1
// baseline (311.871 us; speedup 1.0000x reference)
//
#include <hip/hip_runtime.h>

// Problem constants
#define BB 8192
#define KCNT 50

// Generic fp32 tiled GEMM: C[M,N] = act((A (+A2)) @ W + bias)
// 64x64 output tile per 256-thread block, 4x4 micro-tile per thread.
// LDS layouts padded to stride 68 floats (16B-aligned b128 reads, no bank conflicts).
__global__ __launch_bounds__(256) void gemm_tile(
    const float* __restrict__ A, const float* __restrict__ A2,
    const float* __restrict__ W, const float* __restrict__ bias,
    float* __restrict__ C, int M, int K, int N, int do_relu)
{
    __shared__ float At[64 * 68];  // At[d][m] : A tile transposed
    __shared__ float Ws[64 * 68];  // Ws[d][n]

    const int t  = threadIdx.x;
    const int tx = t & 15;         // col group: cols 4*tx..4*tx+3
    const int ty = t >> 4;         // row group: rows 4*ty..4*ty+3
    const int n0 = blockIdx.x * 64;
    const int m0 = blockIdx.y * 64;
    const int lr = t >> 2;         // loader row 0..63
    const int lc = (t & 3) << 4;   // loader col base (4 float4s at lc+4i)

    float acc[4][4] = {{0.f, 0.f, 0.f, 0.f}, {0.f, 0.f, 0.f, 0.f},
                       {0.f, 0.f, 0.f, 0.f}, {0.f, 0.f, 0.f, 0.f}};

    for (int k0 = 0; k0 < K; k0 += 64) {
        // ---- stage A tile (transposed into At) ----
        const float* Ap = A + (size_t)(m0 + lr) * K + k0 + lc;
        #pragma unroll
        for (int i = 0; i < 4; ++i) {
            float4 v = *(const float4*)(Ap + 4 * i);
            if (A2) {
                const float* A2p = A2 + (size_t)(m0 + lr) * K + k0 + lc;
                float4 w = *(const float4*)(A2p + 4 * i);
                v.x += w.x; v.y += w.y; v.z += w.z; v.w += w.w;
            }
            const int kk = lc + 4 * i;
            At[(kk + 0) * 68 + lr] = v.x;
            At[(kk + 1) * 68 + lr] = v.y;
            At[(kk + 2) * 68 + lr] = v.z;
            At[(kk + 3) * 68 + lr] = v.w;
        }
        // ---- stage W tile (natural layout) ----
        const float* Wp = W + (size_t)(k0 + lr) * N + n0 + lc;
        #pragma unroll
        for (int i = 0; i < 4; ++i)
            *(float4*)&Ws[lr * 68 + lc + 4 * i] = *(const float4*)(Wp + 4 * i);

        __syncthreads();

        // ---- inner product: 2x ds_read_b128 + 16 v_fma_f32 per d ----
        #pragma unroll 16
        for (int d = 0; d < 64; ++d) {
            const float4 a4 = *(const float4*)&At[d * 68 + 4 * ty];
            const float4 w4 = *(const float4*)&Ws[d * 68 + 4 * tx];
            const float av[4] = {a4.x, a4.y, a4.z, a4.w};
            const float wv[4] = {w4.x, w4.y, w4.z, w4.w};
            #pragma unroll
            for (int i = 0; i < 4; ++i)
                #pragma unroll
                for (int j = 0; j < 4; ++j)
                    acc[i][j] = fmaf(av[i], wv[j], acc[i][j]);
        }
        __syncthreads();
    }

    // ---- epilogue: bias (+ReLU), float4 store ----
    float bv[4];
    #pragma unroll
    for (int j = 0; j < 4; ++j) bv[j] = bias[n0 + 4 * tx + j];
    #pragma unroll
    for (int i = 0; i < 4; ++i) {
        float4 o;
        float* op = (float*)&o;
        #pragma unroll
        for (int j = 0; j < 4; ++j) {
            float v = acc[i][j] + bv[j];
            if (do_relu) v = fmaxf(v, 0.f);
            op[j] = v;
        }
        *(float4*)&C[(size_t)(m0 + 4 * ty + i) * N + n0 + 4 * tx] = o;
    }
}

// Knowledge branch: one block per batch element b.
// Gather 64 rows (50 real + 14 pad with mask 0), GEMM vs Wkg (64x64),
// ReLU(dot+bkg)*mask, column-sum over rows -> out[b][64].
__global__ __launch_bounds__(256) void knowledge_kernel(
    const float* __restrict__ kg, const int* __restrict__ idx,
    const int* __restrict__ mask, const float* __restrict__ Wkg,
    const float* __restrict__ bkg, float* __restrict__ out)
{
    __shared__ float At[64 * 68];   // At[d][r] gathered rows, transposed
    __shared__ float Ws[64 * 68];   // Wkg[d][c]
    __shared__ float red[16 * 68];  // partial column sums per row-group
    __shared__ float smask[64];
    __shared__ int   sidx[64];

    const int t  = threadIdx.x;
    const int b  = blockIdx.x;
    const int tx = t & 15;
    const int ty = t >> 4;
    const int lr = t >> 2;
    const int lc = (t & 3) << 4;

    if (t < 64) {
        int id = 0, m = 0;
        if (t < KCNT) {
            id = idx[(size_t)b * KCNT + t];
            m  = mask[(size_t)b * KCNT + t];
        }
        sidx[t]  = id;
        smask[t] = (float)m;
    }
    __syncthreads();

    // gather rows -> At (transposed)
    {
        const float* rp = kg + (size_t)sidx[lr] * 64 + lc;
        #pragma unroll
        for (int i = 0; i < 4; ++i) {
            float4 v = *(const float4*)(rp + 4 * i);
            const int kk = lc + 4 * i;
            At[(kk + 0) * 68 + lr] = v.x;
            At[(kk + 1) * 68 + lr] = v.y;
            At[(kk + 2) * 68 + lr] = v.z;
            At[(kk + 3) * 68 + lr] = v.w;
        }
        const float* Wp = Wkg + lr * 64 + lc;
        #pragma unroll
        for (int i = 0; i < 4; ++i)
            *(float4*)&Ws[lr * 68 + lc + 4 * i] = *(const float4*)(Wp + 4 * i);
    }
    __syncthreads();

    float acc[4][4] = {{0.f, 0.f, 0.f, 0.f}, {0.f, 0.f, 0.f, 0.f},
                       {0.f, 0.f, 0.f, 0.f}, {0.f, 0.f, 0.f, 0.f}};
    #pragma unroll 16
    for (int d = 0; d < 64; ++d) {
        const float4 a4 = *(const float4*)&At[d * 68 + 4 * ty];
        const float4 w4 = *(const float4*)&Ws[d * 68 + 4 * tx];
        const float av[4] = {a4.x, a4.y, a4.z, a4.w};
        const float wv[4] = {w4.x, w4.y, w4.z, w4.w};
        #pragma unroll
        for (int i = 0; i < 4; ++i)
            #pragma unroll
            for (int j = 0; j < 4; ++j)
                acc[i][j] = fmaf(av[i], wv[j], acc[i][j]);
    }

    // ReLU(acc + bkg) * mask, partial sum over this thread's 4 rows
    float bv[4];
    #pragma unroll
    for (int j = 0; j < 4; ++j) bv[j] = bkg[4 * tx + j];
    float part[4] = {0.f, 0.f, 0.f, 0.f};
    #pragma unroll
    for (int i = 0; i < 4; ++i) {
        const float mk = smask[4 * ty + i];
        #pragma unroll
        for (int j = 0; j < 4; ++j)
            part[j] += mk * fmaxf(acc[i][j] + bv[j], 0.f);
    }
    float4 pv;
    pv.x = part[0]; pv.y = part[1]; pv.z = part[2]; pv.w = part[3];
    *(float4*)&red[ty * 68 + 4 * tx] = pv;
    __syncthreads();

    // column reduce over 16 row-groups
    if (t < 64) {
        float s = 0.f;
        #pragma unroll
        for (int g = 0; g < 16; ++g) s += red[g * 68 + t];
        out[(size_t)b * 64 + t] = s;
    }
}

extern "C" void kernel_launch(void* const* d_in, const int* in_sizes, int n_in,
                              void* d_out, int out_size, void* d_ws, size_t ws_size,
                              hipStream_t stream)
{
    const float* x    = (const float*)d_in[0];
    const float* kg   = (const float*)d_in[1];
    const int*   idx  = (const int*)d_in[2];
    const int*   mask = (const int*)d_in[3];
    const float* Wkg  = (const float*)d_in[4];
    const float* bkg  = (const float*)d_in[5];
    const float* W1a  = (const float*)d_in[6];
    const float* b1a  = (const float*)d_in[7];
    const float* W1b  = (const float*)d_in[8];
    const float* b1b  = (const float*)d_in[9];
    const float* W1c  = (const float*)d_in[10];
    const float* b1c  = (const float*)d_in[11];
    const float* W1d  = (const float*)d_in[12];
    const float* b1d  = (const float*)d_in[13];
    const float* W2   = (const float*)d_in[14];
    const float* b2   = (const float*)d_in[15];
    float* out = (float*)d_out;

    // Workspace layout (floats): 8192*(64+128+512+128+64) = 7,340,032 (28 MB)
    float* ws   = (float*)d_ws;
    float* know = ws;                       // [8192, 64]
    float* h1   = know + (size_t)BB * 64;   // [8192, 128]
    float* h2   = h1 + (size_t)BB * 128;    // [8192, 512]
    float* h3   = h2 + (size_t)BB * 512;    // [8192, 128]
    float* h4   = h3 + (size_t)BB * 128;    // [8192, 64]

    knowledge_kernel<<<BB, 256, 0, stream>>>(kg, idx, mask, Wkg, bkg, know);

    // layer1 chain: 512->128->512->128->64, ReLU each
    gemm_tile<<<dim3(2, 128), 256, 0, stream>>>(x,  nullptr, W1a, b1a, h1, BB, 512, 128, 1);
    gemm_tile<<<dim3(8, 128), 256, 0, stream>>>(h1, nullptr, W1b, b1b, h2, BB, 128, 512, 1);
    gemm_tile<<<dim3(2, 128), 256, 0, stream>>>(h2, nullptr, W1c, b1c, h3, BB, 512, 128, 1);
    gemm_tile<<<dim3(1, 128), 256, 0, stream>>>(h3, nullptr, W1d, b1d, h4, BB, 128, 64, 1);

    // final: (knowledge + h4) @ W2 + b2, no ReLU
    gemm_tile<<<dim3(16, 128), 256, 0, stream>>>(h4, know, W2, b2, out, BB, 64, 1024, 0);
}

// Round 2
// 212.227 us; speedup vs baseline: 1.4695x; 1.4695x over previous
//
#include <hip/hip_runtime.h>

#define BB 8192
#define KCNT 50

typedef __attribute__((ext_vector_type(8))) short bf16x8;
typedef __attribute__((ext_vector_type(4))) float f32x4;

__device__ __forceinline__ ushort f2bf(float f) {
    union { float f; unsigned u; } v; v.f = f;
    unsigned r = v.u + 0x7FFFu + ((v.u >> 16) & 1u);
    return (ushort)(r >> 16);
}
__device__ __forceinline__ float bf2f(ushort h) {
    union { unsigned u; float f; } v; v.u = ((unsigned)h) << 16;
    return v.f;
}

// ---- prep: x fp32 -> bf16 (same layout) ----
__global__ __launch_bounds__(256) void convert_f32_bf16(
    const float* __restrict__ src, ushort* __restrict__ dst, int n4)
{
    int gid = blockIdx.x * 256 + threadIdx.x;
    if (gid >= n4) return;
    float4 v = ((const float4*)src)[gid];
    ushort4 o;
    o.x = f2bf(v.x); o.y = f2bf(v.y); o.z = f2bf(v.z); o.w = f2bf(v.w);
    ((ushort4*)dst)[gid] = o;
}

// ---- prep: all 6 weights [K][N] fp32 -> [N][K] bf16 ----
__global__ __launch_bounds__(256) void prep_weights(
    const float* __restrict__ s0, ushort* __restrict__ d0,   // Wkg 64x64
    const float* __restrict__ s1, ushort* __restrict__ d1,   // W1a 512x128
    const float* __restrict__ s2, ushort* __restrict__ d2,   // W1b 128x512
    const float* __restrict__ s3, ushort* __restrict__ d3,   // W1c 512x128
    const float* __restrict__ s4, ushort* __restrict__ d4,   // W1d 128x64
    const float* __restrict__ s5, ushort* __restrict__ d5)   // W2 64x1024
{
    int gid = blockIdx.x * 256 + threadIdx.x;
    const float* s; ushort* d; int K, N, base;
    if      (gid < 4096)   { s = s0; d = d0; K = 64;  N = 64;   base = 0; }
    else if (gid < 69632)  { s = s1; d = d1; K = 512; N = 128;  base = 4096; }
    else if (gid < 135168) { s = s2; d = d2; K = 128; N = 512;  base = 69632; }
    else if (gid < 200704) { s = s3; d = d3; K = 512; N = 128;  base = 135168; }
    else if (gid < 208896) { s = s4; d = d4; K = 128; N = 64;   base = 200704; }
    else if (gid < 274432) { s = s5; d = d5; K = 64;  N = 1024; base = 208896; }
    else return;
    int e = gid - base;          // e = k*N + n  (coalesced read)
    int k = e / N, n = e % N;
    d[n * K + k] = f2bf(s[e]);
}

// ---- bf16 MFMA GEMM: C[M,N] = act((A (+A2)) @ Wt^T + bias) ----
// A [M,K] bf16, Wt [N,K] bf16 (pre-transposed). 128Mx64N block tile,
// 4 waves of 64Mx32N. LDS rows padded to 72 bf16 (2-way bank alias = free).
__global__ __launch_bounds__(256) void gemm_bf16(
    const ushort* __restrict__ A, const ushort* __restrict__ A2,
    const ushort* __restrict__ Wt, const float* __restrict__ bias,
    void* __restrict__ Cout, int K, int N, int relu, int out_bf16)
{
    __shared__ ushort As[128 * 72];
    __shared__ ushort Ws[64 * 72];

    const int t    = threadIdx.x;
    const int m0   = blockIdx.y * 128;
    const int n0   = blockIdx.x * 64;
    const int w    = t >> 6;
    const int lane = t & 63;
    const int ln   = lane & 15;
    const int quad = lane >> 4;
    const int wm   = w & 1;   // M half (64 rows)
    const int wn   = w >> 1;  // N half (32 cols)

    f32x4 acc[4][2];
    #pragma unroll
    for (int i = 0; i < 4; ++i)
        #pragma unroll
        for (int j = 0; j < 2; ++j)
            acc[i][j] = (f32x4){0.f, 0.f, 0.f, 0.f};

    for (int k0 = 0; k0 < K; k0 += 64) {
        __syncthreads();
        // stage A tile: 128 rows x 64 k (8 x 16B segs per row)
        #pragma unroll
        for (int i = 0; i < 4; ++i) {
            int gid = i * 256 + t;
            int row = gid >> 3, seg = gid & 7;
            const uint4* gp = (const uint4*)(A + (size_t)(m0 + row) * K + k0);
            uint4 v = gp[seg];
            if (A2) {
                const uint4* gp2 = (const uint4*)(A2 + (size_t)(m0 + row) * K + k0);
                uint4 v2 = gp2[seg];
                ushort* pa = (ushort*)&v; const ushort* pb = (const ushort*)&v2;
                #pragma unroll
                for (int e = 0; e < 8; ++e) pa[e] = f2bf(bf2f(pa[e]) + bf2f(pb[e]));
            }
            *(uint4*)&As[row * 72 + seg * 8] = v;
        }
        // stage Wt tile: 64 rows x 64 k
        #pragma unroll
        for (int i = 0; i < 2; ++i) {
            int gid = i * 256 + t;
            int row = gid >> 3, seg = gid & 7;
            const uint4* gp = (const uint4*)(Wt + (size_t)(n0 + row) * K + k0);
            *(uint4*)&Ws[row * 72 + seg * 8] = gp[seg];
        }
        __syncthreads();

        #pragma unroll
        for (int s = 0; s < 2; ++s) {
            bf16x8 a[4], b[2];
            #pragma unroll
            for (int mt = 0; mt < 4; ++mt)
                a[mt] = *(const bf16x8*)&As[(wm * 64 + mt * 16 + ln) * 72 + s * 32 + quad * 8];
            #pragma unroll
            for (int nt = 0; nt < 2; ++nt)
                b[nt] = *(const bf16x8*)&Ws[(wn * 32 + nt * 16 + ln) * 72 + s * 32 + quad * 8];
            #pragma unroll
            for (int mt = 0; mt < 4; ++mt)
                #pragma unroll
                for (int nt = 0; nt < 2; ++nt)
                    acc[mt][nt] = __builtin_amdgcn_mfma_f32_16x16x32_bf16(
                        a[mt], b[nt], acc[mt][nt], 0, 0, 0);
        }
    }

    // epilogue: C/D layout col=lane&15, row=quad*4+reg
    float bv[2];
    #pragma unroll
    for (int nt = 0; nt < 2; ++nt) bv[nt] = bias[n0 + wn * 32 + nt * 16 + ln];
    #pragma unroll
    for (int mt = 0; mt < 4; ++mt) {
        #pragma unroll
        for (int nt = 0; nt < 2; ++nt) {
            const int col = n0 + wn * 32 + nt * 16 + ln;
            #pragma unroll
            for (int i = 0; i < 4; ++i) {
                const int row = m0 + wm * 64 + mt * 16 + quad * 4 + i;
                float vv = acc[mt][nt][i] + bv[nt];
                if (relu) vv = fmaxf(vv, 0.f);
                if (out_bf16) ((ushort*)Cout)[(size_t)row * N + col] = f2bf(vv);
                else          ((float*)Cout)[(size_t)row * N + col] = vv;
            }
        }
    }
}

// ---- knowledge branch, bf16 MFMA: 1 wave per batch, 4 batches/block ----
__global__ __launch_bounds__(256) void knowledge_bf16(
    const float* __restrict__ kg, const int* __restrict__ idx,
    const int* __restrict__ mask, const ushort* __restrict__ Wkgt,
    const float* __restrict__ bkg, ushort* __restrict__ know)
{
    __shared__ ushort As[4][64 * 72];
    __shared__ ushort Ws[64 * 72];
    __shared__ float  msk[4][64];
    __shared__ int    sidx[4][64];

    const int t    = threadIdx.x;
    const int w    = t >> 6;
    const int lane = t & 63;
    const int ln   = lane & 15;
    const int quad = lane >> 4;
    const int b    = blockIdx.x * 4 + w;

    {
        int id = 0, mkv = 0;
        if (lane < KCNT) {
            id  = idx[(size_t)b * KCNT + lane];
            mkv = mask[(size_t)b * KCNT + lane];
        }
        sidx[w][lane] = id;
        msk[w][lane]  = (float)mkv;
    }
    // stage Wkgt (shared by all 4 waves)
    #pragma unroll
    for (int i = 0; i < 2; ++i) {
        int gid = i * 256 + t;
        int row = gid >> 3, seg = gid & 7;
        *(uint4*)&Ws[row * 72 + seg * 8] = ((const uint4*)(Wkgt + row * 64))[seg];
    }
    __syncthreads();

    // gather this wave's batch: 16 passes x (4 rows x 16 lanes x float4)
    #pragma unroll 4
    for (int p = 0; p < 16; ++p) {
        const int row = p * 4 + quad;
        ushort4 o;
        if (row < KCNT) {
            const float4 v = *(const float4*)(kg + (size_t)sidx[w][row] * 64 + ln * 4);
            o.x = f2bf(v.x); o.y = f2bf(v.y); o.z = f2bf(v.z); o.w = f2bf(v.w);
        } else {
            o.x = 0; o.y = 0; o.z = 0; o.w = 0;  // padded rows, mask=0
        }
        *(ushort4*)&As[w][row * 72 + ln * 4] = o;
    }

    f32x4 acc[4][4];
    #pragma unroll
    for (int i = 0; i < 4; ++i)
        #pragma unroll
        for (int j = 0; j < 4; ++j)
            acc[i][j] = (f32x4){0.f, 0.f, 0.f, 0.f};

    #pragma unroll
    for (int s = 0; s < 2; ++s) {
        bf16x8 a[4], bb[4];
        #pragma unroll
        for (int mt = 0; mt < 4; ++mt)
            a[mt] = *(const bf16x8*)&As[w][(mt * 16 + ln) * 72 + s * 32 + quad * 8];
        #pragma unroll
        for (int nt = 0; nt < 4; ++nt)
            bb[nt] = *(const bf16x8*)&Ws[(nt * 16 + ln) * 72 + s * 32 + quad * 8];
        #pragma unroll
        for (int mt = 0; mt < 4; ++mt)
            #pragma unroll
            for (int nt = 0; nt < 4; ++nt)
                acc[mt][nt] = __builtin_amdgcn_mfma_f32_16x16x32_bf16(
                    a[mt], bb[nt], acc[mt][nt], 0, 0, 0);
    }

    // relu(c + bkg)*mask, column-sum over 64 rows
    float bv[4];
    #pragma unroll
    for (int nt = 0; nt < 4; ++nt) bv[nt] = bkg[nt * 16 + ln];
    float cs[4] = {0.f, 0.f, 0.f, 0.f};
    #pragma unroll
    for (int mt = 0; mt < 4; ++mt) {
        const float4 mk = *(const float4*)&msk[w][mt * 16 + quad * 4];
        const float mka[4] = {mk.x, mk.y, mk.z, mk.w};
        #pragma unroll
        for (int nt = 0; nt < 4; ++nt)
            #pragma unroll
            for (int i = 0; i < 4; ++i)
                cs[nt] += mka[i] * fmaxf(acc[mt][nt][i] + bv[nt], 0.f);
    }
    #pragma unroll
    for (int nt = 0; nt < 4; ++nt) {
        cs[nt] += __shfl_xor(cs[nt], 16, 64);
        cs[nt] += __shfl_xor(cs[nt], 32, 64);
    }
    if (quad == 0) {
        #pragma unroll
        for (int nt = 0; nt < 4; ++nt)
            know[(size_t)b * 64 + nt * 16 + ln] = f2bf(cs[nt]);
    }
}

extern "C" void kernel_launch(void* const* d_in, const int* in_sizes, int n_in,
                              void* d_out, int out_size, void* d_ws, size_t ws_size,
                              hipStream_t stream)
{
    const float* x    = (const float*)d_in[0];
    const float* kg   = (const float*)d_in[1];
    const int*   idx  = (const int*)d_in[2];
    const int*   mask = (const int*)d_in[3];
    const float* Wkg  = (const float*)d_in[4];
    const float* bkg  = (const float*)d_in[5];
    const float* W1a  = (const float*)d_in[6];
    const float* b1a  = (const float*)d_in[7];
    const float* W1b  = (const float*)d_in[8];
    const float* b1b  = (const float*)d_in[9];
    const float* W1c  = (const float*)d_in[10];
    const float* b1c  = (const float*)d_in[11];
    const float* W1d  = (const float*)d_in[12];
    const float* b1d  = (const float*)d_in[13];
    const float* W2   = (const float*)d_in[14];
    const float* b2   = (const float*)d_in[15];
    float* out = (float*)d_out;

    // ws layout (ushorts): activations + know + transposed bf16 weights (~23.6 MB)
    ushort* xb   = (ushort*)d_ws;                    // [8192][512]
    ushort* h1   = xb   + (size_t)BB * 512;          // [8192][128]
    ushort* h2   = h1   + (size_t)BB * 128;          // [8192][512]
    ushort* h3   = h2   + (size_t)BB * 512;          // [8192][128]
    ushort* h4   = h3   + (size_t)BB * 128;          // [8192][64]
    ushort* know = h4   + (size_t)BB * 64;           // [8192][64]
    ushort* Wkgt = know + (size_t)BB * 64;           // [64][64]
    ushort* W1at = Wkgt + 64 * 64;                   // [128][512]
    ushort* W1bt = W1at + 512 * 128;                 // [512][128]
    ushort* W1ct = W1bt + 128 * 512;                 // [128][512]
    ushort* W1dt = W1ct + 512 * 128;                 // [64][128]
    ushort* W2t  = W1dt + 128 * 64;                  // [1024][64]

    convert_f32_bf16<<<(BB * 512 / 4 + 255) / 256, 256, 0, stream>>>(x, xb, BB * 512 / 4);
    prep_weights<<<(274432 + 255) / 256, 256, 0, stream>>>(
        Wkg, Wkgt, W1a, W1at, W1b, W1bt, W1c, W1ct, W1d, W1dt, W2, W2t);

    knowledge_bf16<<<BB / 4, 256, 0, stream>>>(kg, idx, mask, Wkgt, bkg, know);

    gemm_bf16<<<dim3(2, 64), 256, 0, stream>>>(xb, nullptr, W1at, b1a, h1, 512, 128, 1, 1);
    gemm_bf16<<<dim3(8, 64), 256, 0, stream>>>(h1, nullptr, W1bt, b1b, h2, 128, 512, 1, 1);
    gemm_bf16<<<dim3(2, 64), 256, 0, stream>>>(h2, nullptr, W1ct, b1c, h3, 512, 128, 1, 1);
    gemm_bf16<<<dim3(1, 64), 256, 0, stream>>>(h3, nullptr, W1dt, b1d, h4, 128, 64, 1, 1);
    gemm_bf16<<<dim3(16, 64), 256, 0, stream>>>(h4, know, W2t, b2, (void*)out, 64, 1024, 0, 0);
}

// Round 3
// 178.920 us; speedup vs baseline: 1.7431x; 1.1862x over previous
//
#include <hip/hip_runtime.h>

#define BB 8192
#define KCNT 50

typedef __attribute__((ext_vector_type(8))) short bf16x8;
typedef __attribute__((ext_vector_type(4))) float f32x4;

__device__ __forceinline__ ushort f2bf(float f) {
    union { float f; unsigned u; } v; v.f = f;
    unsigned r = v.u + 0x7FFFu + ((v.u >> 16) & 1u);
    return (ushort)(r >> 16);
}
__device__ __forceinline__ float bf2f(ushort h) {
    union { unsigned u; float f; } v; v.u = ((unsigned)h) << 16;
    return v.f;
}

// ---- prep: all 6 weights [K][N] fp32 -> [N][K] bf16 ----
__global__ __launch_bounds__(256) void prep_weights(
    const float* __restrict__ s0, ushort* __restrict__ d0,   // Wkg 64x64
    const float* __restrict__ s1, ushort* __restrict__ d1,   // W1a 512x128
    const float* __restrict__ s2, ushort* __restrict__ d2,   // W1b 128x512
    const float* __restrict__ s3, ushort* __restrict__ d3,   // W1c 512x128
    const float* __restrict__ s4, ushort* __restrict__ d4,   // W1d 128x64
    const float* __restrict__ s5, ushort* __restrict__ d5)   // W2 64x1024
{
    int gid = blockIdx.x * 256 + threadIdx.x;
    const float* s; ushort* d; int K, N, base;
    if      (gid < 4096)   { s = s0; d = d0; K = 64;  N = 64;   base = 0; }
    else if (gid < 69632)  { s = s1; d = d1; K = 512; N = 128;  base = 4096; }
    else if (gid < 135168) { s = s2; d = d2; K = 128; N = 512;  base = 69632; }
    else if (gid < 200704) { s = s3; d = d3; K = 512; N = 128;  base = 135168; }
    else if (gid < 208896) { s = s4; d = d4; K = 128; N = 64;   base = 200704; }
    else if (gid < 274432) { s = s5; d = d5; K = 64;  N = 1024; base = 208896; }
    else return;
    int e = gid - base;          // e = k*N + n  (coalesced read)
    int k = e / N, n = e % N;
    d[n * K + k] = f2bf(s[e]);
}

// ---- knowledge branch, bf16 MFMA: 1 wave per batch, 4 batches/block ----
__global__ __launch_bounds__(256) void knowledge_bf16(
    const float* __restrict__ kg, const int* __restrict__ idx,
    const int* __restrict__ mask, const ushort* __restrict__ Wkgt,
    const float* __restrict__ bkg, ushort* __restrict__ know)
{
    __shared__ ushort As[4][64 * 72];
    __shared__ ushort Ws[64 * 72];
    __shared__ float  msk[4][64];
    __shared__ int    sidx[4][64];

    const int t    = threadIdx.x;
    const int w    = t >> 6;
    const int lane = t & 63;
    const int ln   = lane & 15;
    const int quad = lane >> 4;
    const int b    = blockIdx.x * 4 + w;

    {
        int id = 0, mkv = 0;
        if (lane < KCNT) {
            id  = idx[(size_t)b * KCNT + lane];
            mkv = mask[(size_t)b * KCNT + lane];
        }
        sidx[w][lane] = id;
        msk[w][lane]  = (float)mkv;
    }
    #pragma unroll
    for (int i = 0; i < 2; ++i) {
        int gid = i * 256 + t;
        int row = gid >> 3, seg = gid & 7;
        *(uint4*)&Ws[row * 72 + seg * 8] = ((const uint4*)(Wkgt + row * 64))[seg];
    }
    __syncthreads();

    // gather this wave's batch: 16 passes x (4 rows x 16 lanes x float4)
    #pragma unroll 4
    for (int p = 0; p < 16; ++p) {
        const int row = p * 4 + quad;
        ushort4 o;
        if (row < KCNT) {
            const float4 v = *(const float4*)(kg + (size_t)sidx[w][row] * 64 + ln * 4);
            o.x = f2bf(v.x); o.y = f2bf(v.y); o.z = f2bf(v.z); o.w = f2bf(v.w);
        } else {
            o.x = 0; o.y = 0; o.z = 0; o.w = 0;
        }
        *(ushort4*)&As[w][row * 72 + ln * 4] = o;
    }

    f32x4 acc[4][4];
    #pragma unroll
    for (int i = 0; i < 4; ++i)
        #pragma unroll
        for (int j = 0; j < 4; ++j)
            acc[i][j] = (f32x4){0.f, 0.f, 0.f, 0.f};

    #pragma unroll
    for (int s = 0; s < 2; ++s) {
        bf16x8 a[4], bb[4];
        #pragma unroll
        for (int mt = 0; mt < 4; ++mt)
            a[mt] = *(const bf16x8*)&As[w][(mt * 16 + ln) * 72 + s * 32 + quad * 8];
        #pragma unroll
        for (int nt = 0; nt < 4; ++nt)
            bb[nt] = *(const bf16x8*)&Ws[(nt * 16 + ln) * 72 + s * 32 + quad * 8];
        #pragma unroll
        for (int mt = 0; mt < 4; ++mt)
            #pragma unroll
            for (int nt = 0; nt < 4; ++nt)
                acc[mt][nt] = __builtin_amdgcn_mfma_f32_16x16x32_bf16(
                    a[mt], bb[nt], acc[mt][nt], 0, 0, 0);
    }

    float bv[4];
    #pragma unroll
    for (int nt = 0; nt < 4; ++nt) bv[nt] = bkg[nt * 16 + ln];
    float cs[4] = {0.f, 0.f, 0.f, 0.f};
    #pragma unroll
    for (int mt = 0; mt < 4; ++mt) {
        const float4 mk = *(const float4*)&msk[w][mt * 16 + quad * 4];
        const float mka[4] = {mk.x, mk.y, mk.z, mk.w};
        #pragma unroll
        for (int nt = 0; nt < 4; ++nt)
            #pragma unroll
            for (int i = 0; i < 4; ++i)
                cs[nt] += mka[i] * fmaxf(acc[mt][nt][i] + bv[nt], 0.f);
    }
    #pragma unroll
    for (int nt = 0; nt < 4; ++nt) {
        cs[nt] += __shfl_xor(cs[nt], 16, 64);
        cs[nt] += __shfl_xor(cs[nt], 32, 64);
    }
    if (quad == 0) {
        #pragma unroll
        for (int nt = 0; nt < 4; ++nt)
            know[(size_t)b * 64 + nt * 16 + ln] = f2bf(cs[nt]);
    }
}

// =================== fused MLP: one block = 32 batch rows ===================
// actA: x / h2 (K up to 512, stride 520)   33.3 KB
// actB: h1 / h3 (K=128, stride 136)         8.7 KB
// actC: know -> h4+know (K=64, stride 72)   4.6 KB
// Wbuf: weight chunk [N<=512][72]          73.7 KB      total ~118 KB -> 1 blk/CU

template<int K, int N, int STRIN, int STROUT>
__device__ __forceinline__ void dense_layer(
    const ushort* actIn, ushort* actOut, const ushort* addIn,
    const ushort* __restrict__ Wt, const float* __restrict__ bias,
    ushort* Wbuf, int t, bool relu)
{
    constexpr int NC = N / 4;        // cols per wave
    constexpr int NT = NC / 16;      // 16-wide n-tiles per wave
    const int w = t >> 6, lane = t & 63, ln = lane & 15, quad = lane >> 4;

    f32x4 acc[2][NT];
    #pragma unroll
    for (int mt = 0; mt < 2; ++mt)
        #pragma unroll
        for (int nt = 0; nt < NT; ++nt)
            acc[mt][nt] = (f32x4){0.f, 0.f, 0.f, 0.f};

    for (int k0 = 0; k0 < K; k0 += 64) {
        __syncthreads();
        // stage Wt chunk [N][64] -> Wbuf [N][72]
        constexpr int PASSES = N * 8 / 256;
        #pragma unroll
        for (int p = 0; p < PASSES; ++p) {
            int gid = p * 256 + t;
            int row = gid >> 3, seg = gid & 7;
            *(uint4*)&Wbuf[row * 72 + seg * 8] =
                *(const uint4*)(Wt + (size_t)row * K + k0 + seg * 8);
        }
        __syncthreads();
        #pragma unroll
        for (int s = 0; s < 2; ++s) {
            bf16x8 a[2];
            #pragma unroll
            for (int mt = 0; mt < 2; ++mt)
                a[mt] = *(const bf16x8*)&actIn[(mt * 16 + ln) * STRIN + k0 + s * 32 + quad * 8];
            #pragma unroll
            for (int nt = 0; nt < NT; ++nt) {
                bf16x8 b = *(const bf16x8*)&Wbuf[(w * NC + nt * 16 + ln) * 72 + s * 32 + quad * 8];
                #pragma unroll
                for (int mt = 0; mt < 2; ++mt)
                    acc[mt][nt] = __builtin_amdgcn_mfma_f32_16x16x32_bf16(
                        a[mt], b, acc[mt][nt], 0, 0, 0);
            }
        }
    }
    // epilogue: bias (+relu) (+addIn), write bf16 to actOut
    #pragma unroll
    for (int nt = 0; nt < NT; ++nt) {
        const int col = w * NC + nt * 16 + ln;
        const float bv = bias[col];
        #pragma unroll
        for (int mt = 0; mt < 2; ++mt)
            #pragma unroll
            for (int i = 0; i < 4; ++i) {
                const int row = mt * 16 + quad * 4 + i;
                float v = acc[mt][nt][i] + bv;
                if (relu) v = fmaxf(v, 0.f);
                if (addIn) v += bf2f(addIn[row * STROUT + col]);
                actOut[row * STROUT + col] = f2bf(v);
            }
    }
}

__global__ __launch_bounds__(256) void fused_mlp(
    const float* __restrict__ x, const ushort* __restrict__ know,
    const ushort* __restrict__ W1at, const float* __restrict__ b1a,
    const ushort* __restrict__ W1bt, const float* __restrict__ b1b,
    const ushort* __restrict__ W1ct, const float* __restrict__ b1c,
    const ushort* __restrict__ W1dt, const float* __restrict__ b1d,
    const ushort* __restrict__ W2t,  const float* __restrict__ b2,
    float* __restrict__ out)
{
    __shared__ ushort actA[32 * 520];
    __shared__ ushort actB[32 * 136];
    __shared__ ushort actC[32 * 72];
    __shared__ ushort Wbuf[512 * 72];

    const int t    = threadIdx.x;
    const int m0   = blockIdx.x * 32;
    const int w    = t >> 6;
    const int lane = t & 63;
    const int ln   = lane & 15;
    const int quad = lane >> 4;

    // phase 0: stage x (fp32 -> bf16) and know tile
    #pragma unroll
    for (int p = 0; p < 16; ++p) {
        int gid = p * 256 + t;
        int row = gid >> 7, c4 = gid & 127;   // 128 float4 per row of 512
        float4 v = *(const float4*)(x + (size_t)(m0 + row) * 512 + c4 * 4);
        ushort4 o;
        o.x = f2bf(v.x); o.y = f2bf(v.y); o.z = f2bf(v.z); o.w = f2bf(v.w);
        *(ushort4*)&actA[row * 520 + c4 * 4] = o;
    }
    {
        int row = t >> 3, seg = t & 7;        // 32 rows x 8 segs of 16B
        *(uint4*)&actC[row * 72 + seg * 8] =
            *(const uint4*)(know + (size_t)(m0 + row) * 64 + seg * 8);
    }

    // phase 1: h1 = relu(x @ W1a + b1a)          512 -> 128
    dense_layer<512, 128, 520, 136>(actA, actB, nullptr, W1at, b1a, Wbuf, t, true);
    // phase 2: h2 = relu(h1 @ W1b + b1b)         128 -> 512
    dense_layer<128, 512, 136, 520>(actB, actA, nullptr, W1bt, b1b, Wbuf, t, true);
    // phase 3: h3 = relu(h2 @ W1c + b1c)         512 -> 128
    dense_layer<512, 128, 520, 136>(actA, actB, nullptr, W1ct, b1c, Wbuf, t, true);
    // phase 4: h4 = relu(h3 @ W1d + b1d) + know  128 -> 64 (in-place add into actC)
    dense_layer<128, 64, 136, 72>(actB, actC, actC, W1dt, b1d, Wbuf, t, true);

    // phase 5: out = actC @ W2t^T + b2, fp32, N=1024 in 4 chunks of 256
    for (int nc = 0; nc < 4; ++nc) {
        __syncthreads();
        #pragma unroll
        for (int p = 0; p < 8; ++p) {
            int gid = p * 256 + t;
            int row = gid >> 3, seg = gid & 7;
            *(uint4*)&Wbuf[row * 72 + seg * 8] =
                *(const uint4*)(W2t + (size_t)(nc * 256 + row) * 64 + seg * 8);
        }
        __syncthreads();
        f32x4 acc[2][4];
        #pragma unroll
        for (int mt = 0; mt < 2; ++mt)
            #pragma unroll
            for (int nt = 0; nt < 4; ++nt)
                acc[mt][nt] = (f32x4){0.f, 0.f, 0.f, 0.f};
        #pragma unroll
        for (int s = 0; s < 2; ++s) {
            bf16x8 a[2];
            #pragma unroll
            for (int mt = 0; mt < 2; ++mt)
                a[mt] = *(const bf16x8*)&actC[(mt * 16 + ln) * 72 + s * 32 + quad * 8];
            #pragma unroll
            for (int nt = 0; nt < 4; ++nt) {
                bf16x8 b = *(const bf16x8*)&Wbuf[(w * 64 + nt * 16 + ln) * 72 + s * 32 + quad * 8];
                #pragma unroll
                for (int mt = 0; mt < 2; ++mt)
                    acc[mt][nt] = __builtin_amdgcn_mfma_f32_16x16x32_bf16(
                        a[mt], b, acc[mt][nt], 0, 0, 0);
            }
        }
        #pragma unroll
        for (int nt = 0; nt < 4; ++nt) {
            const int col = nc * 256 + w * 64 + nt * 16 + ln;
            const float bv = b2[col];
            #pragma unroll
            for (int mt = 0; mt < 2; ++mt)
                #pragma unroll
                for (int i = 0; i < 4; ++i) {
                    const int row = m0 + mt * 16 + quad * 4 + i;
                    out[(size_t)row * 1024 + col] = acc[mt][nt][i] + bv;
                }
        }
    }
}

extern "C" void kernel_launch(void* const* d_in, const int* in_sizes, int n_in,
                              void* d_out, int out_size, void* d_ws, size_t ws_size,
                              hipStream_t stream)
{
    const float* x    = (const float*)d_in[0];
    const float* kg   = (const float*)d_in[1];
    const int*   idx  = (const int*)d_in[2];
    const int*   mask = (const int*)d_in[3];
    const float* Wkg  = (const float*)d_in[4];
    const float* bkg  = (const float*)d_in[5];
    const float* W1a  = (const float*)d_in[6];
    const float* b1a  = (const float*)d_in[7];
    const float* W1b  = (const float*)d_in[8];
    const float* b1b  = (const float*)d_in[9];
    const float* W1c  = (const float*)d_in[10];
    const float* b1c  = (const float*)d_in[11];
    const float* W1d  = (const float*)d_in[12];
    const float* b1d  = (const float*)d_in[13];
    const float* W2   = (const float*)d_in[14];
    const float* b2   = (const float*)d_in[15];
    float* out = (float*)d_out;

    // ws (ushorts): know [8192][64] + transposed bf16 weights (~1.6 MB total)
    ushort* know = (ushort*)d_ws;                    // [8192][64]
    ushort* Wkgt = know + (size_t)BB * 64;           // [64][64]
    ushort* W1at = Wkgt + 64 * 64;                   // [128][512]
    ushort* W1bt = W1at + 512 * 128;                 // [512][128]
    ushort* W1ct = W1bt + 128 * 512;                 // [128][512]
    ushort* W1dt = W1ct + 512 * 128;                 // [64][128]
    ushort* W2t  = W1dt + 128 * 64;                  // [1024][64]

    prep_weights<<<(274432 + 255) / 256, 256, 0, stream>>>(
        Wkg, Wkgt, W1a, W1at, W1b, W1bt, W1c, W1ct, W1d, W1dt, W2, W2t);

    knowledge_bf16<<<BB / 4, 256, 0, stream>>>(kg, idx, mask, Wkgt, bkg, know);

    fused_mlp<<<BB / 32, 256, 0, stream>>>(
        x, know, W1at, b1a, W1bt, b1b, W1ct, b1c, W1dt, b1d, W2t, b2, out);
}